// Round 6
// baseline (86.875 us; speedup 1.0000x reference)
//
#include <hip/hip_runtime.h>
#include <math.h>

#define NB   64
#define NC_  256
#define NH   40
#define NW   40
#define NHW  1600
#define NWIN 64
#define CH   4          // channels per sample block
#define PW   44         // padded LDS row stride (floats), 4-aligned
#define IMS  1852       // per-channel slot: 4 guard + 42*44=1848
// channel image: im = img + cc*IMS + 4; pixel (x,y) at im[(y+1)*44 + x].
// Zeroed: guard img[cc*IMS+0..3], LDS rows 0 & 41 (full 44), cols 40..43 of
// rows 1..40. base = (y0c+1)*44 + x0c with x0c,y0c clamped to [-1,39]:
// all 4 corners base,+1,+44,+45 land in valid or zeroed cells (incl. base=-1
// -> guard, and col -1 -> previous row's col 43, zeroed).

typedef float f32x4 __attribute__((ext_vector_type(4)));

// ---------------------------------------------------------------------------
// Kernel A: window-mean pool of f2 + BN + ReLU. One block per (b, c).
// ---------------------------------------------------------------------------
__global__ __launch_bounds__(256) void pool_bn_kernel(
    const float* __restrict__ feats,
    const float* __restrict__ gd, const float* __restrict__ bed,
    const float* __restrict__ rmd, const float* __restrict__ rvd,
    float* __restrict__ pooled)
{
    __shared__ __align__(16) float img[NHW];
    const int bc = blockIdx.x;          // b*256 + c
    const int b  = bc >> 8;
    const int c  = bc & 255;

    const float4* src4 = (const float4*)(feats + (size_t)bc * NHW);
    for (int i = threadIdx.x; i < NHW / 4; i += 256)
        ((float4*)img)[i] = src4[i];
    __syncthreads();

    if (threadIdx.x < NWIN) {
        const int win = threadIdx.x;
        const int wh  = win >> 3;
        const int ww  = win & 7;
        const int base = (wh * 5) * NW + ww * 5;
        float sum = 0.f;
        #pragma unroll
        for (int i = 0; i < 5; ++i)
            #pragma unroll
            for (int j = 0; j < 5; ++j)
                sum += img[base + i * NW + j];
        float mean = sum * (1.0f / 25.0f);
        float f2m  = (ww < 6) ? (2.0f * mean) : (mean + 1e-5f);
        float inv  = gd[c] / sqrtf(rvd[c] + 1e-5f);
        float v    = f2m * inv + (bed[c] - rmd[c] * inv);
        v = fmaxf(v, 0.0f);
        pooled[((size_t)(b * NWIN + win)) * NC_ + c] = v;
    }
}

// ---------------------------------------------------------------------------
// Kernel B: co = pooled . wd^T + bd, affine M, and per-pixel FOLDED bilinear
// coefficients:
//   cw4[px]  = weights * validity * a_k  (a_k = 2 if clamped corner col < 30
//              else 1 — folds the f2 transform's multiplicative part)
//   ccst[px] = 1e-5 * sum_k wv_k*[clamped col_k >= 30]   (additive part)
//   cbase[px]= (y0c+1)*44 + x0c  (int, may be -1), corners at +0,+1,+44,+45
// ---------------------------------------------------------------------------
__global__ __launch_bounds__(256) void co_M_kernel(
    const float* __restrict__ pooled,
    const float* __restrict__ wd, const float* __restrict__ bd,
    float* __restrict__ Mbuf,
    float4* __restrict__ cw4, int* __restrict__ cbase, float* __restrict__ ccst)
{
    const int blk = blockIdx.x;         // b*64 + win
    const int tid = threadIdx.x;

    __shared__ float red[4][8];
    __shared__ float co[8];
    __shared__ float sM[6];

    const float p = pooled[(size_t)blk * NC_ + tid];
    float part[8];
    #pragma unroll
    for (int o = 0; o < 8; ++o) part[o] = p * wd[o * NC_ + tid];

    const int lane = tid & 63;
    const int wv   = tid >> 6;
    #pragma unroll
    for (int o = 0; o < 8; ++o) {
        float v = part[o];
        #pragma unroll
        for (int off = 32; off > 0; off >>= 1) v += __shfl_down(v, off, 64);
        if (lane == 0) red[wv][o] = v;
    }
    __syncthreads();
    if (tid < 8) co[tid] = red[0][tid] + red[1][tid] + red[2][tid] + red[3][tid] + bd[tid];
    __syncthreads();

    if (tid == 0) {
        const float xr = co[0], yr = co[1], sx = co[2], sy = co[3];
        const float tx0 = co[4], tx1 = co[5], ty0 = co[6], ty1 = co[7];
        const float cx = cosf(xr), sxr = sinf(xr);
        const float cy = cosf(yr), syr = sinf(yr);
        const float s = sx * sy;
        float* m = Mbuf + blk * 6;
        sM[0] = m[0] = (cx * cy - sxr * syr) * s;          // M00
        sM[1] = m[1] = (cx * syr + sxr * cy) * s;          // M01
        sM[2] = m[2] = sx * (cx * ty0 + sxr * ty1) + tx0;  // M02
        sM[3] = m[3] = (-sxr * cy - cx * syr) * s;         // M10
        sM[4] = m[4] = (-sxr * syr + cx * cy) * s;         // M11
        sM[5] = m[5] = sx * (-sxr * ty0 + cx * ty1) + tx1; // M12
    }
    __syncthreads();

    if (cw4 != nullptr && tid < 25) {
        const int b   = blk >> 6;
        const int win = blk & 63;
        const int wh  = win >> 3;
        const int ww  = win & 7;
        const int ii  = tid / 5;
        const int jj  = tid - ii * 5;

        const float wcx = (float)(jj - 2) * (2.0f / 39.0f);
        const float wcy = (float)(ii - 2) * (2.0f / 39.0f);
        const float gx = sM[0] * wcx + sM[1] * wcy + sM[2];
        const float gy = sM[3] * wcx + sM[4] * wcy + sM[5];

        float x = (gx + 1.0f) * 19.5f;
        float y = (gy + 1.0f) * 19.5f;
        x = fminf(fmaxf(x, -1.0e6f), 1.0e6f);
        y = fminf(fmaxf(y, -1.0e6f), 1.0e6f);

        const float x0f = floorf(x), y0f = floorf(y);
        const int x0 = (int)x0f, y0 = (int)y0f;
        const int x1 = x0 + 1,  y1 = y0 + 1;
        const float fx = x - x0f, fy = y - y0f;

        const bool xv0 = (x0 >= 0) & (x0 <= NW - 1);
        const bool xv1 = (x1 >= 0) & (x1 <= NW - 1);
        const bool yv0 = (y0 >= 0) & (y0 <= NH - 1);
        const bool yv1 = (y1 >= 0) & (y1 <= NH - 1);

        // validity-masked bilinear weights
        const float w00 = (1.f - fx) * (1.f - fy) * (float)(xv0 && yv0);
        const float w01 = fx * (1.f - fy) * (float)(xv1 && yv0);
        const float w10 = (1.f - fx) * fy * (float)(xv0 && yv1);
        const float w11 = fx * fy * (float)(xv1 && yv1);

        // fold f2: value = a*feats + d with a,d from clamped corner column
        const int xc0 = min(max(x0, 0), NW - 1);
        const int xc1 = min(max(x1, 0), NW - 1);
        const float a0 = (xc0 < 30) ? 2.f : 1.f;
        const float a1 = (xc1 < 30) ? 2.f : 1.f;
        const float d0 = (xc0 < 30) ? 0.f : 1e-5f;
        const float d1 = (xc1 < 30) ? 0.f : 1e-5f;

        float4 wvec;
        wvec.x = w00 * a0;
        wvec.y = w01 * a1;
        wvec.z = w10 * a0;
        wvec.w = w11 * a1;
        const float cst = w00 * d0 + w01 * d1 + w10 * d0 + w11 * d1;

        const int xb = min(max(x0, -1), NW - 1);
        const int yb = min(max(y0, -1), NH - 1);
        const int base = (yb + 1) * PW + xb;

        const int h = wh * 5 + ii;
        const int w = ww * 5 + jj;
        const int pidx = b * NHW + h * NW + w;
        cw4[pidx]   = wvec;
        cbase[pidx] = base;
        ccst[pidx]  = cst;
    }
}

// ---------------------------------------------------------------------------
// Kernel C: bilinear sample from RAW feats (transform folded into coeffs).
// One block per (b, cgroup of CH=4); 320 threads; each item = (channel,
// 4-pixel group): 6 coalesced 16B coeff loads, 8 ds_read2_b32 gathers,
// 16 FMA, one nontemporal dwordx4 store. 1600 items / 320 thr = 5 each.
// ---------------------------------------------------------------------------
__global__ __launch_bounds__(320) void sample_fold_kernel(
    const float* __restrict__ feats,
    const float4* __restrict__ cw4, const int* __restrict__ cbase,
    const float* __restrict__ ccst,
    float* __restrict__ out)
{
    __shared__ __align__(16) float img[CH * IMS];

    const int blk = blockIdx.x;         // b*(256/CH) + cg
    const int b   = blk >> 6;           // 256/CH = 64
    const int cg  = blk & 63;
    const int c0  = cg * CH;

    // zero guards + borders: 63 float4 per channel.
    for (int i = threadIdx.x; i < CH * 63; i += 320) {
        const int cc = i / 63;
        const int t  = i - cc * 63;
        float* im = img + cc * IMS + 4;
        f32x4 z = {0.f, 0.f, 0.f, 0.f};
        if (t == 0)       *(f32x4*)(img + cc * IMS) = z;            // guard
        else if (t <= 11) *(f32x4*)(im + (t - 1) * 4) = z;          // row 0
        else if (t <= 22) *(f32x4*)(im + 41 * PW + (t - 12) * 4) = z; // row 41
        else              *(f32x4*)(im + (t - 22) * PW + 40) = z;   // cols 40..43
    }

    // stage CH raw images: pure float4 copy into padded rows (aligned b128).
    for (int i = threadIdx.x; i < CH * (NHW / 4); i += 320) {
        const int cc = i / (NHW / 4);
        const int j  = i - cc * (NHW / 4);      // float4 index in image
        const int r  = j / (NW / 4);            // image row
        const int c4 = j - r * (NW / 4);
        const f32x4 v = *((const f32x4*)(feats + (size_t)(b * NC_ + c0 + cc) * NHW) + j);
        *(f32x4*)(img + cc * IMS + 4 + (r + 1) * PW + c4 * 4) = v;
    }
    __syncthreads();

    const float4* cwb = cw4   + (size_t)b * NHW;
    const int4*   cbb = (const int4*)(cbase + (size_t)b * NHW);
    const float4* csb = (const float4*)(ccst + (size_t)b * NHW);

    #pragma unroll
    for (int k = 0; k < 5; ++k) {
        const int item = k * 320 + threadIdx.x;  // 0..1599
        const int cc   = item / 400;
        const int g    = item - cc * 400;        // 4-pixel group

        const int4   bs = cbb[g];
        const float4 ct = csb[g];
        const float4 w0 = cwb[g * 4 + 0];
        const float4 w1 = cwb[g * 4 + 1];
        const float4 w2 = cwb[g * 4 + 2];
        const float4 w3 = cwb[g * 4 + 3];

        const float* im = img + cc * IMS + 4;
        f32x4 r;
        r.x = ct.x + w0.x * im[bs.x] + w0.y * im[bs.x + 1]
                   + w0.z * im[bs.x + PW] + w0.w * im[bs.x + PW + 1];
        r.y = ct.y + w1.x * im[bs.y] + w1.y * im[bs.y + 1]
                   + w1.z * im[bs.y + PW] + w1.w * im[bs.y + PW + 1];
        r.z = ct.z + w2.x * im[bs.z] + w2.y * im[bs.z + 1]
                   + w2.z * im[bs.z + PW] + w2.w * im[bs.z + PW + 1];
        r.w = ct.w + w3.x * im[bs.w] + w3.y * im[bs.w + 1]
                   + w3.z * im[bs.w + PW] + w3.w * im[bs.w + PW + 1];

        f32x4* dst = (f32x4*)(out + (size_t)(b * NC_ + c0 + cc) * NHW + g * 4);
        __builtin_nontemporal_store(r, dst);
    }
}

// ---------------------------------------------------------------------------
// Fallback sampler (round-1 style) if ws_size is too small for coeffs.
// ---------------------------------------------------------------------------
__global__ __launch_bounds__(256) void sample_kernel(
    const float* __restrict__ feats,
    const float* __restrict__ Mbuf,
    float* __restrict__ out)
{
    __shared__ __align__(16) float img[NHW];
    __shared__ float Ml[NWIN * 6];

    const int bc = blockIdx.x;
    const int b  = bc >> 8;

    const float4* src4 = (const float4*)(feats + (size_t)bc * NHW);
    for (int i = threadIdx.x; i < NHW / 4; i += 256) {
        float4 v = src4[i];
        const int j = i % (NW / 4);
        if (j < 7)      { v.x *= 2.f; v.y *= 2.f; v.z *= 2.f; v.w *= 2.f; }
        else if (j == 7){ v.x *= 2.f; v.y *= 2.f; v.z += 1e-5f; v.w += 1e-5f; }
        else            { v.x += 1e-5f; v.y += 1e-5f; v.z += 1e-5f; v.w += 1e-5f; }
        ((float4*)img)[i] = v;
    }
    for (int i = threadIdx.x; i < NWIN * 6; i += 256)
        Ml[i] = Mbuf[b * NWIN * 6 + i];
    __syncthreads();

    float* dst = out + (size_t)bc * NHW;
    for (int idx = threadIdx.x; idx < NHW; idx += 256) {
        const int h  = idx / NW;
        const int w  = idx - h * NW;
        const int wh = h / 5, ii = h - wh * 5;
        const int ww = w / 5, jj = w - ww * 5;
        const float* m = &Ml[(wh * 8 + ww) * 6];

        const float wcx = (float)(jj - 2) * (2.0f / 39.0f);
        const float wcy = (float)(ii - 2) * (2.0f / 39.0f);
        const float gx = m[0] * wcx + m[1] * wcy + m[2];
        const float gy = m[3] * wcx + m[4] * wcy + m[5];

        float x = (gx + 1.0f) * 19.5f;
        float y = (gy + 1.0f) * 19.5f;
        x = fminf(fmaxf(x, -1.0e6f), 1.0e6f);
        y = fminf(fmaxf(y, -1.0e6f), 1.0e6f);

        const float x0f = floorf(x), y0f = floorf(y);
        const int x0 = (int)x0f, y0 = (int)y0f;
        const int x1 = x0 + 1,  y1 = y0 + 1;
        const float fx = x - x0f, fy = y - y0f;

        const bool xv0 = (x0 >= 0) & (x0 <= NW - 1);
        const bool xv1 = (x1 >= 0) & (x1 <= NW - 1);
        const bool yv0 = (y0 >= 0) & (y0 <= NH - 1);
        const bool yv1 = (y1 >= 0) & (y1 <= NH - 1);

        const int xc0 = min(max(x0, 0), NW - 1);
        const int xc1 = min(max(x1, 0), NW - 1);
        const int yc0 = min(max(y0, 0), NH - 1);
        const int yc1 = min(max(y1, 0), NH - 1);

        float acc = 0.f;
        acc += img[yc0 * NW + xc0] * ((1.f - fx) * (1.f - fy)) * (float)(xv0 && yv0);
        acc += img[yc0 * NW + xc1] * (fx * (1.f - fy)) * (float)(xv1 && yv0);
        acc += img[yc1 * NW + xc0] * ((1.f - fx) * fy) * (float)(xv0 && yv1);
        acc += img[yc1 * NW + xc1] * (fx * fy) * (float)(xv1 && yv1);

        dst[idx] = acc;
    }
}

// ---------------------------------------------------------------------------
extern "C" void kernel_launch(void* const* d_in, const int* in_sizes, int n_in,
                              void* d_out, int out_size, void* d_ws, size_t ws_size,
                              hipStream_t stream)
{
    (void)in_sizes; (void)n_in; (void)out_size;

    const float* feats = (const float*)d_in[0];
    // d_in[1..8] (w1,b1,g1,be1,rm1,rv1,w2,b2) are dead code in the reference.
    const float* gd  = (const float*)d_in[9];
    const float* bed = (const float*)d_in[10];
    const float* rmd = (const float*)d_in[11];
    const float* rvd = (const float*)d_in[12];
    const float* wd  = (const float*)d_in[13];
    const float* bd  = (const float*)d_in[14];

    float* out = (float*)d_out;

    // pooled (4 MB) staged in the front of d_out — fully overwritten by the
    // sample kernel afterwards (stream-ordered).
    float* pooled = out;

    // d_ws: Mbuf [96 KB] | cw4 [1.6 MB] | cbase [0.4 MB] | ccst [0.4 MB]
    const size_t CW_OFF = 98304;
    const size_t CW_B   = (size_t)NB * NHW * sizeof(float4);   // 1638400
    const size_t CB_OFF = CW_OFF + CW_B;                       // 1736704
    const size_t CB_B   = (size_t)NB * NHW * sizeof(int);      // 409600
    const size_t CS_OFF = CB_OFF + CB_B;                       // 2146304
    const size_t CS_B   = (size_t)NB * NHW * sizeof(float);    // 409600
    const bool fast = (ws_size >= CS_OFF + CS_B);

    float*  Mbuf  = (float*)d_ws;
    float4* cw4   = fast ? (float4*)((char*)d_ws + CW_OFF) : nullptr;
    int*    cbase = fast ? (int*)((char*)d_ws + CB_OFF)    : nullptr;
    float*  ccst  = fast ? (float*)((char*)d_ws + CS_OFF)  : nullptr;

    pool_bn_kernel<<<NB * NC_, 256, 0, stream>>>(feats, gd, bed, rmd, rvd, pooled);
    co_M_kernel<<<NB * NWIN, 256, 0, stream>>>(pooled, wd, bd, Mbuf, cw4, cbase, ccst);
    if (fast)
        sample_fold_kernel<<<NB * (NC_ / CH), 320, 0, stream>>>(feats, cw4, cbase, ccst, out);
    else
        sample_kernel<<<NB * NC_, 256, 0, stream>>>(feats, Mbuf, out);
}

// Round 7
// 73.349 us; speedup vs baseline: 1.1844x; 1.1844x over previous
//
#include <hip/hip_runtime.h>
#include <math.h>

#define NB   64
#define NC_  256
#define NH   40
#define NW   40
#define NHW  1600
#define NWIN 64
#define CH   4          // channels per sample block
#define PW   44         // padded LDS row stride (floats), 4-aligned
#define IMS  1852       // per-channel slot: 4 guard + 42*44=1848
// channel image: im = img + cc*IMS + 4; pixel (x,y) at im[(y+1)*44 + x].
// Zeroed: guard [0..3], padded rows 0 & 41, cols 40..43 of rows 1..40.
// base = (y0c+1)*44 + x0c, x0c,y0c clamped to [-1,39]; corners at
// +0,+1,+44,+45 always land in valid or zeroed cells (base=-1 -> guard).

typedef float f32x4 __attribute__((ext_vector_type(4)));

// ---------------------------------------------------------------------------
// Kernel A: window-mean pool of f2 + BN + ReLU. One block per (b, c).
// ---------------------------------------------------------------------------
__global__ __launch_bounds__(256) void pool_bn_kernel(
    const float* __restrict__ feats,
    const float* __restrict__ gd, const float* __restrict__ bed,
    const float* __restrict__ rmd, const float* __restrict__ rvd,
    float* __restrict__ pooled)
{
    __shared__ __align__(16) float img[NHW];
    const int bc = blockIdx.x;          // b*256 + c
    const int b  = bc >> 8;
    const int c  = bc & 255;

    const float4* src4 = (const float4*)(feats + (size_t)bc * NHW);
    for (int i = threadIdx.x; i < NHW / 4; i += 256)
        ((float4*)img)[i] = src4[i];
    __syncthreads();

    if (threadIdx.x < NWIN) {
        const int win = threadIdx.x;
        const int wh  = win >> 3;
        const int ww  = win & 7;
        const int base = (wh * 5) * NW + ww * 5;
        float sum = 0.f;
        #pragma unroll
        for (int i = 0; i < 5; ++i)
            #pragma unroll
            for (int j = 0; j < 5; ++j)
                sum += img[base + i * NW + j];
        float mean = sum * (1.0f / 25.0f);
        float f2m  = (ww < 6) ? (2.0f * mean) : (mean + 1e-5f);
        float inv  = gd[c] / sqrtf(rvd[c] + 1e-5f);
        float v    = f2m * inv + (bed[c] - rmd[c] * inv);
        v = fmaxf(v, 0.0f);
        pooled[((size_t)(b * NWIN + win)) * NC_ + c] = v;
    }
}

// ---------------------------------------------------------------------------
// Kernel B: co = pooled . wd^T + bd, affine M, per-pixel FOLDED bilinear
// coefficients:
//   cw4[px] = weights*validity*a_k (a=2 if clamped corner col<30 else 1)
//   cbc[px] = {base, bitcast(cst)}; cst = 1e-5 * sum_k wv_k*[col_k>=30]
// ---------------------------------------------------------------------------
__global__ __launch_bounds__(256) void co_M_kernel(
    const float* __restrict__ pooled,
    const float* __restrict__ wd, const float* __restrict__ bd,
    float* __restrict__ Mbuf,
    float4* __restrict__ cw4, int2* __restrict__ cbc)
{
    const int blk = blockIdx.x;         // b*64 + win
    const int tid = threadIdx.x;

    __shared__ float red[4][8];
    __shared__ float co[8];
    __shared__ float sM[6];

    const float p = pooled[(size_t)blk * NC_ + tid];
    float part[8];
    #pragma unroll
    for (int o = 0; o < 8; ++o) part[o] = p * wd[o * NC_ + tid];

    const int lane = tid & 63;
    const int wv   = tid >> 6;
    #pragma unroll
    for (int o = 0; o < 8; ++o) {
        float v = part[o];
        #pragma unroll
        for (int off = 32; off > 0; off >>= 1) v += __shfl_down(v, off, 64);
        if (lane == 0) red[wv][o] = v;
    }
    __syncthreads();
    if (tid < 8) co[tid] = red[0][tid] + red[1][tid] + red[2][tid] + red[3][tid] + bd[tid];
    __syncthreads();

    if (tid == 0) {
        const float xr = co[0], yr = co[1], sx = co[2], sy = co[3];
        const float tx0 = co[4], tx1 = co[5], ty0 = co[6], ty1 = co[7];
        const float cx = cosf(xr), sxr = sinf(xr);
        const float cy = cosf(yr), syr = sinf(yr);
        const float s = sx * sy;
        float* m = Mbuf + blk * 6;
        sM[0] = m[0] = (cx * cy - sxr * syr) * s;          // M00
        sM[1] = m[1] = (cx * syr + sxr * cy) * s;          // M01
        sM[2] = m[2] = sx * (cx * ty0 + sxr * ty1) + tx0;  // M02
        sM[3] = m[3] = (-sxr * cy - cx * syr) * s;         // M10
        sM[4] = m[4] = (-sxr * syr + cx * cy) * s;         // M11
        sM[5] = m[5] = sx * (-sxr * ty0 + cx * ty1) + tx1; // M12
    }
    __syncthreads();

    if (cw4 != nullptr && tid < 25) {
        const int b   = blk >> 6;
        const int win = blk & 63;
        const int wh  = win >> 3;
        const int ww  = win & 7;
        const int ii  = tid / 5;
        const int jj  = tid - ii * 5;

        const float wcx = (float)(jj - 2) * (2.0f / 39.0f);
        const float wcy = (float)(ii - 2) * (2.0f / 39.0f);
        const float gx = sM[0] * wcx + sM[1] * wcy + sM[2];
        const float gy = sM[3] * wcx + sM[4] * wcy + sM[5];

        float x = (gx + 1.0f) * 19.5f;
        float y = (gy + 1.0f) * 19.5f;
        x = fminf(fmaxf(x, -1.0e6f), 1.0e6f);
        y = fminf(fmaxf(y, -1.0e6f), 1.0e6f);

        const float x0f = floorf(x), y0f = floorf(y);
        const int x0 = (int)x0f, y0 = (int)y0f;
        const int x1 = x0 + 1,  y1 = y0 + 1;
        const float fx = x - x0f, fy = y - y0f;

        const bool xv0 = (x0 >= 0) & (x0 <= NW - 1);
        const bool xv1 = (x1 >= 0) & (x1 <= NW - 1);
        const bool yv0 = (y0 >= 0) & (y0 <= NH - 1);
        const bool yv1 = (y1 >= 0) & (y1 <= NH - 1);

        const float w00 = (1.f - fx) * (1.f - fy) * (float)(xv0 && yv0);
        const float w01 = fx * (1.f - fy) * (float)(xv1 && yv0);
        const float w10 = (1.f - fx) * fy * (float)(xv0 && yv1);
        const float w11 = fx * fy * (float)(xv1 && yv1);

        // fold f2: value = a*feats + d by clamped corner column
        const int xc0 = min(max(x0, 0), NW - 1);
        const int xc1 = min(max(x1, 0), NW - 1);
        const float a0 = (xc0 < 30) ? 2.f : 1.f;
        const float a1 = (xc1 < 30) ? 2.f : 1.f;
        const float d0 = (xc0 < 30) ? 0.f : 1e-5f;
        const float d1 = (xc1 < 30) ? 0.f : 1e-5f;

        float4 wvec;
        wvec.x = w00 * a0;
        wvec.y = w01 * a1;
        wvec.z = w10 * a0;
        wvec.w = w11 * a1;
        const float cst = (w00 + w10) * d0 + (w01 + w11) * d1;

        const int xb = min(max(x0, -1), NW - 1);
        const int yb = min(max(y0, -1), NH - 1);
        const int base = (yb + 1) * PW + xb;

        const int h = wh * 5 + ii;
        const int w = ww * 5 + jj;
        const int pidx = b * NHW + h * NW + w;
        cw4[pidx] = wvec;
        cbc[pidx] = make_int2(base, __float_as_int(cst));
    }
}

// ---------------------------------------------------------------------------
// Kernel C: lean sampler. One block per (b, cgroup of CH=4); 320 threads.
// Staging: 4 groups x 80 threads, each group copies one raw channel image
// (pure float4 -> ds_write_b128, aligned, no transform, no div in loop).
// Gather: thread = pixel, channel-inner; per px: 24B coeff, 8 ds_read2,
// 16 FMA, 4 coalesced nontemporal stores.
// ---------------------------------------------------------------------------
__global__ __launch_bounds__(320) void sample_lean_kernel(
    const float* __restrict__ feats,
    const float4* __restrict__ cw4, const int2* __restrict__ cbc,
    float* __restrict__ out)
{
    __shared__ __align__(16) float img[CH * IMS];

    const int blk = blockIdx.x;         // b*(256/CH) + cg
    const int b   = blk >> 6;           // 256/CH = 64
    const int cg  = blk & 63;
    const int c0  = cg * CH;

    // zero guards + borders: 63 float4 per channel.
    for (int i = threadIdx.x; i < CH * 63; i += 320) {
        const int cc = i / 63;
        const int t  = i - cc * 63;
        float* im = img + cc * IMS + 4;
        f32x4 z = {0.f, 0.f, 0.f, 0.f};
        if (t == 0)       *(f32x4*)(img + cc * IMS) = z;              // guard
        else if (t <= 11) *(f32x4*)(im + (t - 1) * 4) = z;            // row 0
        else if (t <= 22) *(f32x4*)(im + 41 * PW + (t - 12) * 4) = z; // row 41
        else              *(f32x4*)(im + (t - 22) * PW + 40) = z;     // cols 40..43
    }

    // stage CH raw images: group g (80 threads) owns channel g.
    {
        const int g   = threadIdx.x / 80;       // channel within group
        const int r80 = threadIdx.x - g * 80;   // 0..79
        const int rb  = r80 / 10;               // row offset within 8-row band
        const int cb  = r80 - rb * 10;          // float4 col 0..9
        const float* src = feats + (size_t)(b * NC_ + c0 + g) * NHW;
        float* dst = img + g * IMS + 4 + PW;    // interior row 1 (image row 0)
        #pragma unroll
        for (int m = 0; m < 5; ++m) {
            const f32x4 v = *((const f32x4*)src + (m * 80 + r80));
            *(f32x4*)(dst + (m * 8 + rb) * PW + cb * 4) = v;
        }
    }
    __syncthreads();

    const float4* cwb = cw4 + (size_t)b * NHW;
    const int2*   cbb = cbc + (size_t)b * NHW;
    float* dstb = out + (size_t)(b * NC_ + c0) * NHW;

    #pragma unroll
    for (int k = 0; k < 5; ++k) {
        const int px = k * 320 + threadIdx.x;
        const float4 wv = cwb[px];
        const int2   bc = cbb[px];
        const int   base = bc.x;
        const float cst  = __int_as_float(bc.y);
        #pragma unroll
        for (int cc = 0; cc < CH; ++cc) {
            const float* ip = img + cc * IMS + 4 + base;
            const float r = cst + wv.x * ip[0]  + wv.y * ip[1]
                                + wv.z * ip[PW] + wv.w * ip[PW + 1];
            __builtin_nontemporal_store(r, &dstb[(size_t)cc * NHW + px]);
        }
    }
}

// ---------------------------------------------------------------------------
// Fallback sampler (round-1 style) if ws_size is too small for coeffs.
// ---------------------------------------------------------------------------
__global__ __launch_bounds__(256) void sample_kernel(
    const float* __restrict__ feats,
    const float* __restrict__ Mbuf,
    float* __restrict__ out)
{
    __shared__ __align__(16) float img[NHW];
    __shared__ float Ml[NWIN * 6];

    const int bc = blockIdx.x;
    const int b  = bc >> 8;

    const float4* src4 = (const float4*)(feats + (size_t)bc * NHW);
    for (int i = threadIdx.x; i < NHW / 4; i += 256) {
        float4 v = src4[i];
        const int j = i % (NW / 4);
        if (j < 7)      { v.x *= 2.f; v.y *= 2.f; v.z *= 2.f; v.w *= 2.f; }
        else if (j == 7){ v.x *= 2.f; v.y *= 2.f; v.z += 1e-5f; v.w += 1e-5f; }
        else            { v.x += 1e-5f; v.y += 1e-5f; v.z += 1e-5f; v.w += 1e-5f; }
        ((float4*)img)[i] = v;
    }
    for (int i = threadIdx.x; i < NWIN * 6; i += 256)
        Ml[i] = Mbuf[b * NWIN * 6 + i];
    __syncthreads();

    float* dst = out + (size_t)bc * NHW;
    for (int idx = threadIdx.x; idx < NHW; idx += 256) {
        const int h  = idx / NW;
        const int w  = idx - h * NW;
        const int wh = h / 5, ii = h - wh * 5;
        const int ww = w / 5, jj = w - ww * 5;
        const float* m = &Ml[(wh * 8 + ww) * 6];

        const float wcx = (float)(jj - 2) * (2.0f / 39.0f);
        const float wcy = (float)(ii - 2) * (2.0f / 39.0f);
        const float gx = m[0] * wcx + m[1] * wcy + m[2];
        const float gy = m[3] * wcx + m[4] * wcy + m[5];

        float x = (gx + 1.0f) * 19.5f;
        float y = (gy + 1.0f) * 19.5f;
        x = fminf(fmaxf(x, -1.0e6f), 1.0e6f);
        y = fminf(fmaxf(y, -1.0e6f), 1.0e6f);

        const float x0f = floorf(x), y0f = floorf(y);
        const int x0 = (int)x0f, y0 = (int)y0f;
        const int x1 = x0 + 1,  y1 = y0 + 1;
        const float fx = x - x0f, fy = y - y0f;

        const bool xv0 = (x0 >= 0) & (x0 <= NW - 1);
        const bool xv1 = (x1 >= 0) & (x1 <= NW - 1);
        const bool yv0 = (y0 >= 0) & (y0 <= NH - 1);
        const bool yv1 = (y1 >= 0) & (y1 <= NH - 1);

        const int xc0 = min(max(x0, 0), NW - 1);
        const int xc1 = min(max(x1, 0), NW - 1);
        const int yc0 = min(max(y0, 0), NH - 1);
        const int yc1 = min(max(y1, 0), NH - 1);

        float acc = 0.f;
        acc += img[yc0 * NW + xc0] * ((1.f - fx) * (1.f - fy)) * (float)(xv0 && yv0);
        acc += img[yc0 * NW + xc1] * (fx * (1.f - fy)) * (float)(xv1 && yv0);
        acc += img[yc1 * NW + xc0] * ((1.f - fx) * fy) * (float)(xv0 && yv1);
        acc += img[yc1 * NW + xc1] * (fx * fy) * (float)(xv1 && yv1);

        dst[idx] = acc;
    }
}

// ---------------------------------------------------------------------------
extern "C" void kernel_launch(void* const* d_in, const int* in_sizes, int n_in,
                              void* d_out, int out_size, void* d_ws, size_t ws_size,
                              hipStream_t stream)
{
    (void)in_sizes; (void)n_in; (void)out_size;

    const float* feats = (const float*)d_in[0];
    // d_in[1..8] (w1,b1,g1,be1,rm1,rv1,w2,b2) are dead code in the reference.
    const float* gd  = (const float*)d_in[9];
    const float* bed = (const float*)d_in[10];
    const float* rmd = (const float*)d_in[11];
    const float* rvd = (const float*)d_in[12];
    const float* wd  = (const float*)d_in[13];
    const float* bd  = (const float*)d_in[14];

    float* out = (float*)d_out;

    // pooled (4 MB) staged in the front of d_out — fully overwritten by the
    // sample kernel afterwards (stream-ordered).
    float* pooled = out;

    // d_ws: Mbuf [96 KB] | cw4 [1.6 MB] | cbc [0.8 MB]  (total 2.44 MB)
    const size_t CW_OFF  = 98304;
    const size_t CW_B    = (size_t)NB * NHW * sizeof(float4);   // 1638400
    const size_t CBC_OFF = CW_OFF + CW_B;                       // 1736704
    const size_t CBC_B   = (size_t)NB * NHW * sizeof(int2);     // 819200
    const bool fast = (ws_size >= CBC_OFF + CBC_B);

    float*  Mbuf = (float*)d_ws;
    float4* cw4  = fast ? (float4*)((char*)d_ws + CW_OFF)  : nullptr;
    int2*   cbc  = fast ? (int2*)((char*)d_ws + CBC_OFF)   : nullptr;

    pool_bn_kernel<<<NB * NC_, 256, 0, stream>>>(feats, gd, bed, rmd, rvd, pooled);
    co_M_kernel<<<NB * NWIN, 256, 0, stream>>>(pooled, wd, bd, Mbuf, cw4, cbc);
    if (fast)
        sample_lean_kernel<<<NB * (NC_ / CH), 320, 0, stream>>>(feats, cw4, cbc, out);
    else
        sample_kernel<<<NB * NC_, 256, 0, stream>>>(feats, Mbuf, out);
}